// Round 17
// baseline (99.700 us; speedup 1.0000x reference)
//
#include <hip/hip_runtime.h>
#include <math.h>

#define SUPPORT 1.5f

typedef unsigned short ushort_t;
typedef short bf16x8 __attribute__((ext_vector_type(8)));
typedef float f32x4 __attribute__((ext_vector_type(4)));

__device__ __forceinline__ float bf2f(unsigned short h) {
    union { unsigned int u; float f; } c;
    c.u = ((unsigned int)h) << 16;
    return c.f;
}
__device__ __forceinline__ unsigned short f2bf(float f) {
    union { float f; unsigned int u; } c;
    c.f = f;
    unsigned int lsb = (c.u >> 16) & 1u;
    c.u += 0x7fffu + lsb;   // round-to-nearest-even
    return (unsigned short)(c.u >> 16);
}

__device__ __forceinline__ void hat4(float u, float h[4]) {
#pragma unroll
    for (int j = 0; j < 4; ++j) {
        float c = -1.0f + j * (2.0f / 3.0f);
        h[j] = fmaxf(0.0f, 1.0f - fabsf(u - c) * 1.5f);
    }
}

__device__ __forceinline__ void coeff16(float2 A, float2 B, bool neg, float* o) {
    float rx = (A.x - B.x) / SUPPORT;
    float ry = (A.y - B.y) / SUPPORT;
    if (neg) { rx = -rx; ry = -ry; }
    float dx = fminf(fmaxf(rx, -1.0f), 1.0f);
    float dy = fminf(fmaxf(ry, -1.0f), 1.0f);
    float r  = sqrtf(dx * dx + dy * dy) * 2.0f - 1.0f;
    float th = atan2f(dy, dx) / 3.14159265358979323846f;
    float hr[4], ht[4];
    hat4(r, hr);
    hat4(th, ht);
#pragma unroll
    for (int a = 0; a < 4; ++a)
#pragma unroll
        for (int b = 0; b < 4; ++b)
            o[a * 4 + b] = hr[a] * ht[b];
}

__device__ __forceinline__ int lower_bound(const int* __restrict__ arr, int E, int key) {
    int lo = 0, hi = E;
    while (lo < hi) {
        int mid = (lo + hi) >> 1;
        if (arr[mid] < key) lo = mid + 1; else hi = mid;
    }
    return lo;
}

__device__ __forceinline__ void packW(const float* __restrict__ WA,
                                      const float* __restrict__ WB,
                                      const float* __restrict__ fcW,
                                      ushort_t* __restrict__ Wp, int CIN, int idx) {
    int j8   = idx & 7;
    int lane = (idx >> 3) & 63;
    int tile = (idx >> 9) & 3;
    int ks   = idx >> 11;
    int kk = ks * 32 + ((lane >> 4) << 3) + j8;
    int o  = tile * 16 + (lane & 15);
    int KC = 16 * CIN;
    float v = (kk < KC) ? ((o < 32) ? WA[(size_t)kk * 32 + o] : WB[(size_t)kk * 32 + (o - 32)])
                        : fcW[(size_t)(kk - KC) * 64 + o];
    Wp[idx] = f2bf(v);
}

// ---------------- fused prologue: coeffs + CSR offsets + W packing + biases ----------------
__global__ void prologue_kernel(
    const float2* __restrict__ fPos, const float2* __restrict__ bPos,
    const int* __restrict__ fe_i, const int* __restrict__ fe_j,
    const int* __restrict__ be_f, const int* __restrict__ be_b,
    const float* __restrict__ W4, const float* __restrict__ W5,
    const float* __restrict__ fcW1, const float* __restrict__ b4,
    const float* __restrict__ b5, const float* __restrict__ fcb1,
    const float* __restrict__ W6, const float* __restrict__ W7,
    const float* __restrict__ fcW2, const float* __restrict__ b6,
    const float* __restrict__ b7, const float* __restrict__ fcb2,
    float* __restrict__ f_coeff, float* __restrict__ b_coeff,
    int* __restrict__ f_off, int* __restrict__ b_off,
    ushort_t* __restrict__ Wp2, float* __restrict__ bias2,
    ushort_t* __restrict__ Wp3, float* __restrict__ bias3,
    int EF, int EB, int NF) {
    int idx = blockIdx.x * 256 + threadIdx.x;
    if (idx < EF) {
        float co[16];
        coeff16(fPos[fe_j[idx]], fPos[fe_i[idx]], true, co);
        float* o = f_coeff + (size_t)idx * 16;
#pragma unroll
        for (int i = 0; i < 16; ++i) o[i] = co[i];
        return;
    }
    idx -= EF;
    if (idx < EB) {
        float co[16];
        coeff16(bPos[be_b[idx]], fPos[be_f[idx]], false, co);
        float* o = b_coeff + (size_t)idx * 16;
#pragma unroll
        for (int i = 0; i < 16; ++i) o[i] = co[i];
        return;
    }
    idx -= EB;
    if (idx < NF + 1) { f_off[idx] = lower_bound(fe_i, EF, idx); return; }
    idx -= NF + 1;
    if (idx < NF + 1) { b_off[idx] = lower_bound(be_f, EB, idx); return; }
    idx -= NF + 1;
    if (idx < 64) { bias2[idx] = ((idx < 32) ? b4[idx] : b5[idx - 32]) + fcb1[idx]; return; }
    idx -= 64;
    if (idx < 51 * 2048) { packW(W4, W5, fcW1, Wp2, 96, idx); return; }
    idx -= 51 * 2048;
    if (idx < 64) { bias3[idx] = ((idx < 32) ? b6[idx] : b7[idx - 32]) + fcb2[idx]; return; }
    idx -= 64;
    if (idx < 34 * 2048) { packW(W6, W7, fcW2, Wp3, 64, idx); return; }
}

// ---------------- layer 1: 4-wide masked edge unroll, W columns hoisted ----------------
__global__ void layer1_kernel(const float* __restrict__ fluidFeats,
                              const float* __restrict__ boundaryFeats,
                              const float* __restrict__ fcW0, const float* __restrict__ fcb0,
                              const float* __restrict__ W0, const float* __restrict__ b0,
                              const float* __restrict__ W1, const float* __restrict__ b1,
                              const float* __restrict__ W2, const float* __restrict__ b2,
                              const float* __restrict__ W3, const float* __restrict__ b3,
                              const int* __restrict__ f_off, const int* __restrict__ fe_j,
                              const float* __restrict__ f_coeff,
                              const int* __restrict__ b_off, const int* __restrict__ be_b,
                              const float* __restrict__ b_coeff,
                              ushort_t* __restrict__ A1b) {
    int n = blockIdx.x;
    int t = threadIdx.x;
    if (t >= 96) return;
    float val;
    if (t < 32) {
        val = fluidFeats[n * 2] * fcW0[t] + fluidFeats[n * 2 + 1] * fcW0[32 + t] + fcb0[t];
    } else if (t < 64) {
        int oc = t - 32;
        const float* W = (oc < 16) ? W0 : W1;
        int o16 = oc & 15;
        float wk[32];
#pragma unroll
        for (int k = 0; k < 16; ++k) {
            wk[2 * k + 0] = W[(k * 2 + 0) * 16 + o16];
            wk[2 * k + 1] = W[(k * 2 + 1) * 16 + o16];
        }
        float s = (oc < 16) ? b0[o16] : b1[o16];
        int e0 = f_off[n], e1 = f_off[n + 1];
        for (int e = e0; e < e1; e += 4) {
            int ee[4];
            float msk[4];
#pragma unroll
            for (int u = 0; u < 4; ++u) {
                ee[u] = (e + u < e1) ? e + u : e;
                msk[u] = (e + u < e1) ? 1.0f : 0.0f;
            }
            int sn[4];
#pragma unroll
            for (int u = 0; u < 4; ++u) sn[u] = fe_j[ee[u]];
            float4 c4[4][4];
#pragma unroll
            for (int u = 0; u < 4; ++u) {
                const float4* cf4 = (const float4*)(f_coeff + (size_t)ee[u] * 16);
#pragma unroll
                for (int q = 0; q < 4; ++q) c4[u][q] = cf4[q];
            }
            float2 fv[4];
#pragma unroll
            for (int u = 0; u < 4; ++u)
                fv[u] = *(const float2*)(fluidFeats + (size_t)sn[u] * 2);
#pragma unroll
            for (int u = 0; u < 4; ++u) {
                float f0 = fv[u].x * msk[u], f1 = fv[u].y * msk[u];
                const float* cf = (const float*)&c4[u][0];
                float acc = 0.0f;
#pragma unroll
                for (int k = 0; k < 16; ++k)
                    acc += cf[k] * (f0 * wk[2 * k] + f1 * wk[2 * k + 1]);
                s += acc;
            }
        }
        val = s;
    } else {
        int oc = t - 64;
        const float* W = (oc < 16) ? W2 : W3;
        int o16 = oc & 15;
        float wk[48];
#pragma unroll
        for (int k = 0; k < 16; ++k) {
            wk[3 * k + 0] = W[(k * 3 + 0) * 16 + o16];
            wk[3 * k + 1] = W[(k * 3 + 1) * 16 + o16];
            wk[3 * k + 2] = W[(k * 3 + 2) * 16 + o16];
        }
        float s = (oc < 16) ? b2[o16] : b3[o16];
        int e0 = b_off[n], e1 = b_off[n + 1];
        for (int e = e0; e < e1; e += 4) {
            int ee[4];
            float msk[4];
#pragma unroll
            for (int u = 0; u < 4; ++u) {
                ee[u] = (e + u < e1) ? e + u : e;
                msk[u] = (e + u < e1) ? 1.0f : 0.0f;
            }
            int sn[4];
#pragma unroll
            for (int u = 0; u < 4; ++u) sn[u] = be_b[ee[u]];
            float4 c4[4][4];
#pragma unroll
            for (int u = 0; u < 4; ++u) {
                const float4* cf4 = (const float4*)(b_coeff + (size_t)ee[u] * 16);
#pragma unroll
                for (int q = 0; q < 4; ++q) c4[u][q] = cf4[q];
            }
            float bf[4][3];
#pragma unroll
            for (int u = 0; u < 4; ++u) {
                bf[u][0] = boundaryFeats[(size_t)sn[u] * 3 + 0];
                bf[u][1] = boundaryFeats[(size_t)sn[u] * 3 + 1];
                bf[u][2] = boundaryFeats[(size_t)sn[u] * 3 + 2];
            }
#pragma unroll
            for (int u = 0; u < 4; ++u) {
                float f0 = bf[u][0] * msk[u], f1 = bf[u][1] * msk[u], f2 = bf[u][2] * msk[u];
                const float* cf = (const float*)&c4[u][0];
                float acc = 0.0f;
#pragma unroll
                for (int k = 0; k < 16; ++k)
                    acc += cf[k] * (f0 * wk[3 * k] + f1 * wk[3 * k + 1] + f2 * wk[3 * k + 2]);
                s += acc;
            }
        }
        val = s;
    }
    A1b[(size_t)n * 96 + t] = f2bf(fmaxf(val, 0.0f));
}

// ---------------- conv: 8 nodes/block, 1 node/wave, pipelined 1-edge gather + MFMA ----------------
// __launch_bounds__(512, 8): cap VGPR at 64 -> 8 waves/SIMD, 4 blocks/CU (LDS ~30KB).
// Phase-1 staging slimmed (3x uint4 + acc[EPT] ~ 50 VGPR) so the cap does not spill.
template <int CIN, bool RELU, bool RESID, bool FINAL>
__global__ __launch_bounds__(512, 8) void conv_mfma_kernel(
    const ushort_t* __restrict__ Xb,
    const int* __restrict__ f_off, const int* __restrict__ fe_j,
    const float* __restrict__ f_coeff,
    const ushort_t* __restrict__ Wp, const float* __restrict__ bias,
    const ushort_t* __restrict__ XresB,
    void* __restrict__ OUT, int NF) {
    constexpr int KTOT   = 17 * CIN;        // 1632 or 1088
    constexpr int KSTEPS = KTOT / 32;       // 51 or 34
    constexpr int STRIDE = KTOT + 8;
    constexpr int EPT = CIN / 4;            // 24 or 16 bf16 per lane
    constexpr int NU4 = EPT / 8;            // 3 or 2

    __shared__ ushort_t Gl[8 * STRIDE];
    __shared__ float red[4][64][4];

    const int t = threadIdx.x;
    const int wv = t >> 6;
    const int lane = t & 63;
    const int nb = blockIdx.x * 8;

    // ---- phase 1: one node per wave, software-pipelined edge loop ----
    {
        int n = nb + wv;
        if (n > NF - 1) n = NF - 1;
        const int k  = lane >> 2;
        const int i0 = (lane & 3) * EPT;

        float acc[EPT];
#pragma unroll
        for (int s = 0; s < EPT; ++s) acc[s] = 0.0f;

        int e0 = f_off[n], e1 = f_off[n + 1];
        int sN = 0; float cN = 0.0f;
        if (e0 < e1) {
            sN = fe_j[e0];
            cN = f_coeff[(size_t)e0 * 16 + k];
        }
        for (int e = e0; e < e1; ++e) {
            int sC = sN; float cC = cN;
            if (e + 1 < e1) {                       // prefetch next edge's index+coeff
                sN = fe_j[e + 1];
                cN = f_coeff[(size_t)(e + 1) * 16 + k];
            }
            const uint4* xp = (const uint4*)(Xb + (size_t)sC * CIN + i0);
            uint4 r[NU4];
#pragma unroll
            for (int q = 0; q < NU4; ++q) r[q] = xp[q];
#pragma unroll
            for (int q = 0; q < NU4; ++q) {
                unsigned int w[4] = {r[q].x, r[q].y, r[q].z, r[q].w};
#pragma unroll
                for (int j = 0; j < 4; ++j) {
                    float lo = bf2f((unsigned short)(w[j] & 0xffff));
                    float hi = bf2f((unsigned short)(w[j] >> 16));
                    if (RELU) { lo = fmaxf(lo, 0.f); hi = fmaxf(hi, 0.f); }
                    int s = q * 8 + j * 2;
                    acc[s + 0] = fmaf(cC, lo, acc[s + 0]);
                    acc[s + 1] = fmaf(cC, hi, acc[s + 1]);
                }
            }
        }

        ushort_t* grow = Gl + wv * STRIDE;
        ushort_t* gp = grow + k * CIN + i0;
#pragma unroll
        for (int q = 0; q < NU4; ++q) {
            uint4 o;
            o.x = (unsigned int)f2bf(acc[q*8+0]) | ((unsigned int)f2bf(acc[q*8+1]) << 16);
            o.y = (unsigned int)f2bf(acc[q*8+2]) | ((unsigned int)f2bf(acc[q*8+3]) << 16);
            o.z = (unsigned int)f2bf(acc[q*8+4]) | ((unsigned int)f2bf(acc[q*8+5]) << 16);
            o.w = (unsigned int)f2bf(acc[q*8+6]) | ((unsigned int)f2bf(acc[q*8+7]) << 16);
            *(uint4*)(gp + q * 8) = o;
        }
        for (int i = lane; i < CIN; i += 64) {
            ushort_t v = Xb[(size_t)n * CIN + i];
            if (RELU && (v & 0x8000)) v = 0;
            grow[16 * CIN + i] = v;
        }
    }
    __syncthreads();

    // ---- phase 2: MFMA; A rows 8-15 duplicate rows 0-7 (stores masked) ----
    const int ot = wv & 3;
    const int kh = wv >> 2;
    f32x4 cacc = {0.f, 0.f, 0.f, 0.f};
    const ushort_t* garow = Gl + (lane & 7) * STRIDE + ((lane >> 4) << 3);
    const ushort_t* wpp = Wp + ((size_t)(ot * 64 + lane) << 3);
    for (int ks = kh; ks < KSTEPS; ks += 2) {
        bf16x8 a = *(const bf16x8*)(garow + ks * 32);
        bf16x8 b = *(const bf16x8*)(wpp + (size_t)ks * 2048);
        cacc = __builtin_amdgcn_mfma_f32_16x16x32_bf16(a, b, cacc, 0, 0, 0);
    }
    if (kh == 1) {
        red[ot][lane][0] = cacc[0];
        red[ot][lane][1] = cacc[1];
        red[ot][lane][2] = cacc[2];
        red[ot][lane][3] = cacc[3];
    }
    __syncthreads();
    if (kh == 0) {
        int o = ot * 16 + (lane & 15);
        float bo = bias[o];
#pragma unroll
        for (int r = 0; r < 4; ++r) {
            int row = ((lane >> 4) << 2) + r;
            int node = nb + row;
            if (row < 8 && node < NF) {
                float s = cacc[r] + red[ot][lane][r] + bo;
                if (RESID) s += bf2f(XresB[(size_t)node * 64 + o]);
                if (FINAL) {
                    ((float*)OUT)[(size_t)node * 64 + o] = s * (1.0f / 128.0f);
                } else {
                    ((ushort_t*)OUT)[(size_t)node * 64 + o] = f2bf(s);
                }
            }
        }
    }
}

extern "C" void kernel_launch(void* const* d_in, const int* in_sizes, int n_in,
                              void* d_out, int out_size, void* d_ws, size_t ws_size,
                              hipStream_t stream) {
    const float* fluidPos      = (const float*)d_in[0];
    const float* boundaryPos   = (const float*)d_in[1];
    const float* fluidFeats    = (const float*)d_in[2];
    const float* boundaryFeats = (const float*)d_in[3];
    const int* fe_i = (const int*)d_in[4];
    const int* fe_j = (const int*)d_in[5];
    const int* be_f = (const int*)d_in[6];
    const int* be_b = (const int*)d_in[7];
    const float* W[8];
    const float* bb[8];
    for (int c = 0; c < 8; ++c) {
        W[c]  = (const float*)d_in[8 + 2 * c];
        bb[c] = (const float*)d_in[9 + 2 * c];
    }
    const float* fcW0 = (const float*)d_in[24];
    const float* fcb0 = (const float*)d_in[25];
    const float* fcW1 = (const float*)d_in[26];
    const float* fcb1 = (const float*)d_in[27];
    const float* fcW2 = (const float*)d_in[28];
    const float* fcb2 = (const float*)d_in[29];

    int NF = in_sizes[0] / 2;
    int EF = in_sizes[4];
    int EB = in_sizes[6];

    // ---- workspace layout (f32 units) ----
    float* ws = (float*)d_ws;
    size_t p = 0;
    float* f_coeff = ws + p;  p += (size_t)EF * 16;
    float* b_coeff = ws + p;  p += (size_t)EB * 16;
    ushort_t* A1b  = (ushort_t*)(ws + p);  p += (size_t)NF * 48;   // NF*96 bf16
    ushort_t* ans2b= (ushort_t*)(ws + p);  p += (size_t)NF * 32;   // NF*64 bf16
    int*   f_off   = (int*)(ws + p);  p += (size_t)((NF + 4) & ~3);
    int*   b_off   = (int*)(ws + p);  p += (size_t)((NF + 4) & ~3);
    ushort_t* Wp2  = (ushort_t*)(ws + p);  p += 1632 * 32;   // 1632*64 bf16
    float* bias2   = ws + p;  p += 64;
    ushort_t* Wp3  = (ushort_t*)(ws + p);  p += 1088 * 32;
    float* bias3   = ws + p;  p += 64;

    int totalPro = EF + EB + 2 * (NF + 1) + 64 + 51 * 2048 + 64 + 34 * 2048;
    prologue_kernel<<<(totalPro + 255) / 256, 256, 0, stream>>>(
        (const float2*)fluidPos, (const float2*)boundaryPos,
        fe_i, fe_j, be_f, be_b,
        W[4], W[5], fcW1, bb[4], bb[5], fcb1,
        W[6], W[7], fcW2, bb[6], bb[7], fcb2,
        f_coeff, b_coeff, f_off, b_off,
        Wp2, bias2, Wp3, bias3, EF, EB, NF);

    layer1_kernel<<<NF, 128, 0, stream>>>(fluidFeats, boundaryFeats, fcW0, fcb0,
                                          W[0], bb[0], W[1], bb[1], W[2], bb[2], W[3], bb[3],
                                          f_off, fe_j, f_coeff, b_off, be_b, b_coeff, A1b);

    int nblk = (NF + 7) / 8;
    conv_mfma_kernel<96, false, false, false><<<nblk, 512, 0, stream>>>(
        A1b, f_off, fe_j, f_coeff, Wp2, bias2, nullptr, ans2b, NF);
    conv_mfma_kernel<64, true, true, true><<<nblk, 512, 0, stream>>>(
        ans2b, f_off, fe_j, f_coeff, Wp3, bias3, ans2b, d_out, NF);
}

// Round 18
// 98.354 us; speedup vs baseline: 1.0137x; 1.0137x over previous
//
#include <hip/hip_runtime.h>
#include <math.h>

#define SUPPORT 1.5f

typedef unsigned short ushort_t;
typedef short bf16x8 __attribute__((ext_vector_type(8)));
typedef float f32x4 __attribute__((ext_vector_type(4)));

__device__ __forceinline__ float bf2f(unsigned short h) {
    union { unsigned int u; float f; } c;
    c.u = ((unsigned int)h) << 16;
    return c.f;
}
__device__ __forceinline__ unsigned short f2bf(float f) {
    union { float f; unsigned int u; } c;
    c.f = f;
    unsigned int lsb = (c.u >> 16) & 1u;
    c.u += 0x7fffu + lsb;   // round-to-nearest-even
    return (unsigned short)(c.u >> 16);
}

__device__ __forceinline__ void hat4(float u, float h[4]) {
#pragma unroll
    for (int j = 0; j < 4; ++j) {
        float c = -1.0f + j * (2.0f / 3.0f);
        h[j] = fmaxf(0.0f, 1.0f - fabsf(u - c) * 1.5f);
    }
}

__device__ __forceinline__ void coeff16(float2 A, float2 B, bool neg, float* o) {
    float rx = (A.x - B.x) / SUPPORT;
    float ry = (A.y - B.y) / SUPPORT;
    if (neg) { rx = -rx; ry = -ry; }
    float dx = fminf(fmaxf(rx, -1.0f), 1.0f);
    float dy = fminf(fmaxf(ry, -1.0f), 1.0f);
    float r  = sqrtf(dx * dx + dy * dy) * 2.0f - 1.0f;
    float th = atan2f(dy, dx) / 3.14159265358979323846f;
    float hr[4], ht[4];
    hat4(r, hr);
    hat4(th, ht);
#pragma unroll
    for (int a = 0; a < 4; ++a)
#pragma unroll
        for (int b = 0; b < 4; ++b)
            o[a * 4 + b] = hr[a] * ht[b];
}

__device__ __forceinline__ int lower_bound(const int* __restrict__ arr, int E, int key) {
    int lo = 0, hi = E;
    while (lo < hi) {
        int mid = (lo + hi) >> 1;
        if (arr[mid] < key) lo = mid + 1; else hi = mid;
    }
    return lo;
}

__device__ __forceinline__ void packW(const float* __restrict__ WA,
                                      const float* __restrict__ WB,
                                      const float* __restrict__ fcW,
                                      ushort_t* __restrict__ Wp, int CIN, int idx) {
    int j8   = idx & 7;
    int lane = (idx >> 3) & 63;
    int tile = (idx >> 9) & 3;
    int ks   = idx >> 11;
    int kk = ks * 32 + ((lane >> 4) << 3) + j8;
    int o  = tile * 16 + (lane & 15);
    int KC = 16 * CIN;
    float v = (kk < KC) ? ((o < 32) ? WA[(size_t)kk * 32 + o] : WB[(size_t)kk * 32 + (o - 32)])
                        : fcW[(size_t)(kk - KC) * 64 + o];
    Wp[idx] = f2bf(v);
}

// ---------------- fused prologue: coeffs + CSR offsets + W packing + biases ----------------
__global__ void prologue_kernel(
    const float2* __restrict__ fPos, const float2* __restrict__ bPos,
    const int* __restrict__ fe_i, const int* __restrict__ fe_j,
    const int* __restrict__ be_f, const int* __restrict__ be_b,
    const float* __restrict__ W4, const float* __restrict__ W5,
    const float* __restrict__ fcW1, const float* __restrict__ b4,
    const float* __restrict__ b5, const float* __restrict__ fcb1,
    const float* __restrict__ W6, const float* __restrict__ W7,
    const float* __restrict__ fcW2, const float* __restrict__ b6,
    const float* __restrict__ b7, const float* __restrict__ fcb2,
    float* __restrict__ f_coeff, float* __restrict__ b_coeff,
    int* __restrict__ f_off, int* __restrict__ b_off,
    ushort_t* __restrict__ Wp2, float* __restrict__ bias2,
    ushort_t* __restrict__ Wp3, float* __restrict__ bias3,
    int EF, int EB, int NF) {
    int idx = blockIdx.x * 256 + threadIdx.x;
    if (idx < EF) {
        float co[16];
        coeff16(fPos[fe_j[idx]], fPos[fe_i[idx]], true, co);
        float* o = f_coeff + (size_t)idx * 16;
#pragma unroll
        for (int i = 0; i < 16; ++i) o[i] = co[i];
        return;
    }
    idx -= EF;
    if (idx < EB) {
        float co[16];
        coeff16(bPos[be_b[idx]], fPos[be_f[idx]], false, co);
        float* o = b_coeff + (size_t)idx * 16;
#pragma unroll
        for (int i = 0; i < 16; ++i) o[i] = co[i];
        return;
    }
    idx -= EB;
    if (idx < NF + 1) { f_off[idx] = lower_bound(fe_i, EF, idx); return; }
    idx -= NF + 1;
    if (idx < NF + 1) { b_off[idx] = lower_bound(be_f, EB, idx); return; }
    idx -= NF + 1;
    if (idx < 64) { bias2[idx] = ((idx < 32) ? b4[idx] : b5[idx - 32]) + fcb1[idx]; return; }
    idx -= 64;
    if (idx < 51 * 2048) { packW(W4, W5, fcW1, Wp2, 96, idx); return; }
    idx -= 51 * 2048;
    if (idx < 64) { bias3[idx] = ((idx < 32) ? b6[idx] : b7[idx - 32]) + fcb2[idx]; return; }
    idx -= 64;
    if (idx < 34 * 2048) { packW(W6, W7, fcW2, Wp3, 64, idx); return; }
}

// ---------------- layer 1: 4-wide masked edge unroll, W columns hoisted ----------------
__global__ void layer1_kernel(const float* __restrict__ fluidFeats,
                              const float* __restrict__ boundaryFeats,
                              const float* __restrict__ fcW0, const float* __restrict__ fcb0,
                              const float* __restrict__ W0, const float* __restrict__ b0,
                              const float* __restrict__ W1, const float* __restrict__ b1,
                              const float* __restrict__ W2, const float* __restrict__ b2,
                              const float* __restrict__ W3, const float* __restrict__ b3,
                              const int* __restrict__ f_off, const int* __restrict__ fe_j,
                              const float* __restrict__ f_coeff,
                              const int* __restrict__ b_off, const int* __restrict__ be_b,
                              const float* __restrict__ b_coeff,
                              ushort_t* __restrict__ A1b) {
    int n = blockIdx.x;
    int t = threadIdx.x;
    if (t >= 96) return;
    float val;
    if (t < 32) {
        val = fluidFeats[n * 2] * fcW0[t] + fluidFeats[n * 2 + 1] * fcW0[32 + t] + fcb0[t];
    } else if (t < 64) {
        int oc = t - 32;
        const float* W = (oc < 16) ? W0 : W1;
        int o16 = oc & 15;
        float wk[32];
#pragma unroll
        for (int k = 0; k < 16; ++k) {
            wk[2 * k + 0] = W[(k * 2 + 0) * 16 + o16];
            wk[2 * k + 1] = W[(k * 2 + 1) * 16 + o16];
        }
        float s = (oc < 16) ? b0[o16] : b1[o16];
        int e0 = f_off[n], e1 = f_off[n + 1];
        for (int e = e0; e < e1; e += 4) {
            int ee[4];
            float msk[4];
#pragma unroll
            for (int u = 0; u < 4; ++u) {
                ee[u] = (e + u < e1) ? e + u : e;
                msk[u] = (e + u < e1) ? 1.0f : 0.0f;
            }
            int sn[4];
#pragma unroll
            for (int u = 0; u < 4; ++u) sn[u] = fe_j[ee[u]];
            float4 c4[4][4];
#pragma unroll
            for (int u = 0; u < 4; ++u) {
                const float4* cf4 = (const float4*)(f_coeff + (size_t)ee[u] * 16);
#pragma unroll
                for (int q = 0; q < 4; ++q) c4[u][q] = cf4[q];
            }
            float2 fv[4];
#pragma unroll
            for (int u = 0; u < 4; ++u)
                fv[u] = *(const float2*)(fluidFeats + (size_t)sn[u] * 2);
#pragma unroll
            for (int u = 0; u < 4; ++u) {
                float f0 = fv[u].x * msk[u], f1 = fv[u].y * msk[u];
                const float* cf = (const float*)&c4[u][0];
                float acc = 0.0f;
#pragma unroll
                for (int k = 0; k < 16; ++k)
                    acc += cf[k] * (f0 * wk[2 * k] + f1 * wk[2 * k + 1]);
                s += acc;
            }
        }
        val = s;
    } else {
        int oc = t - 64;
        const float* W = (oc < 16) ? W2 : W3;
        int o16 = oc & 15;
        float wk[48];
#pragma unroll
        for (int k = 0; k < 16; ++k) {
            wk[3 * k + 0] = W[(k * 3 + 0) * 16 + o16];
            wk[3 * k + 1] = W[(k * 3 + 1) * 16 + o16];
            wk[3 * k + 2] = W[(k * 3 + 2) * 16 + o16];
        }
        float s = (oc < 16) ? b2[o16] : b3[o16];
        int e0 = b_off[n], e1 = b_off[n + 1];
        for (int e = e0; e < e1; e += 4) {
            int ee[4];
            float msk[4];
#pragma unroll
            for (int u = 0; u < 4; ++u) {
                ee[u] = (e + u < e1) ? e + u : e;
                msk[u] = (e + u < e1) ? 1.0f : 0.0f;
            }
            int sn[4];
#pragma unroll
            for (int u = 0; u < 4; ++u) sn[u] = be_b[ee[u]];
            float4 c4[4][4];
#pragma unroll
            for (int u = 0; u < 4; ++u) {
                const float4* cf4 = (const float4*)(b_coeff + (size_t)ee[u] * 16);
#pragma unroll
                for (int q = 0; q < 4; ++q) c4[u][q] = cf4[q];
            }
            float bf[4][3];
#pragma unroll
            for (int u = 0; u < 4; ++u) {
                bf[u][0] = boundaryFeats[(size_t)sn[u] * 3 + 0];
                bf[u][1] = boundaryFeats[(size_t)sn[u] * 3 + 1];
                bf[u][2] = boundaryFeats[(size_t)sn[u] * 3 + 2];
            }
#pragma unroll
            for (int u = 0; u < 4; ++u) {
                float f0 = bf[u][0] * msk[u], f1 = bf[u][1] * msk[u], f2 = bf[u][2] * msk[u];
                const float* cf = (const float*)&c4[u][0];
                float acc = 0.0f;
#pragma unroll
                for (int k = 0; k < 16; ++k)
                    acc += cf[k] * (f0 * wk[3 * k] + f1 * wk[3 * k + 1] + f2 * wk[3 * k + 2]);
                s += acc;
            }
        }
        val = s;
    }
    A1b[(size_t)n * 96 + t] = f2bf(fmaxf(val, 0.0f));
}

// ---------------- fused conv: buildG(LDS) + MFMA + epilogue; 8 waves / 16 nodes ----------------
template <int CIN, bool RELU, bool RESID, bool FINAL>
__global__ __launch_bounds__(512, 4) void conv_mfma_kernel(
    const ushort_t* __restrict__ Xb,
    const int* __restrict__ f_off, const int* __restrict__ fe_j,
    const float* __restrict__ f_coeff,
    const ushort_t* __restrict__ Wp, const float* __restrict__ bias,
    const ushort_t* __restrict__ XresB,
    void* __restrict__ OUT, int NF) {
    constexpr int KTOT   = 17 * CIN;        // 1632 or 1088
    constexpr int KSTEPS = KTOT / 32;       // 51 or 34
    constexpr int STRIDE = KTOT + 8;
    constexpr int EPT = CIN / 4;            // 24 or 16 bf16 per lane
    constexpr int NU4 = EPT / 8;            // 3 or 2

    __shared__ ushort_t Gl[16 * STRIDE];
    __shared__ float red[4][64][4];

    const int t = threadIdx.x;
    const int wv = t >> 6;
    const int lane = t & 63;
    const int nb = blockIdx.x * 16;

    const int k  = lane >> 2;
    const int i0 = (lane & 3) * EPT;
    for (int s2 = 0; s2 < 2; ++s2) {
        int lnode = wv * 2 + s2;
        int n = nb + lnode;
        if (n > NF - 1) n = NF - 1;

        float acc[EPT];
#pragma unroll
        for (int s = 0; s < EPT; ++s) acc[s] = 0.0f;

        int e0 = f_off[n], e1 = f_off[n + 1];
        for (int e = e0; e < e1; e += 4) {
            int ea = e;
            int eb = (e + 1 < e1) ? e + 1 : e;
            int ec = (e + 2 < e1) ? e + 2 : e;
            int ed = (e + 3 < e1) ? e + 3 : e;
            int s0 = fe_j[ea], s1 = fe_j[eb], s2i = fe_j[ec], s3 = fe_j[ed];
            float c0 = f_coeff[(size_t)ea * 16 + k];
            float c1 = f_coeff[(size_t)eb * 16 + k];
            float c2 = f_coeff[(size_t)ec * 16 + k];
            float c3 = f_coeff[(size_t)ed * 16 + k];
            c1 = (e + 1 < e1) ? c1 : 0.0f;
            c2 = (e + 2 < e1) ? c2 : 0.0f;
            c3 = (e + 3 < e1) ? c3 : 0.0f;
            const uint4* x0 = (const uint4*)(Xb + (size_t)s0 * CIN + i0);
            const uint4* x1 = (const uint4*)(Xb + (size_t)s1 * CIN + i0);
            const uint4* x2 = (const uint4*)(Xb + (size_t)s2i * CIN + i0);
            const uint4* x3 = (const uint4*)(Xb + (size_t)s3 * CIN + i0);
            uint4 r0[NU4], r1[NU4], r2[NU4], r3[NU4];
#pragma unroll
            for (int q = 0; q < NU4; ++q) r0[q] = x0[q];
#pragma unroll
            for (int q = 0; q < NU4; ++q) r1[q] = x1[q];
#pragma unroll
            for (int q = 0; q < NU4; ++q) r2[q] = x2[q];
#pragma unroll
            for (int q = 0; q < NU4; ++q) r3[q] = x3[q];
#pragma unroll
            for (int q = 0; q < NU4; ++q) {
                unsigned int w0[4] = {r0[q].x, r0[q].y, r0[q].z, r0[q].w};
                unsigned int w1[4] = {r1[q].x, r1[q].y, r1[q].z, r1[q].w};
                unsigned int w2[4] = {r2[q].x, r2[q].y, r2[q].z, r2[q].w};
                unsigned int w3[4] = {r3[q].x, r3[q].y, r3[q].z, r3[q].w};
#pragma unroll
                for (int j = 0; j < 4; ++j) {
                    int s = q * 8 + j * 2;
#define EDGEFMA(wj, cc)                                                        \
                    {                                                          \
                        float lo = bf2f((unsigned short)(wj[j] & 0xffff));     \
                        float hi = bf2f((unsigned short)(wj[j] >> 16));        \
                        if (RELU) { lo = fmaxf(lo, 0.f); hi = fmaxf(hi, 0.f); }\
                        acc[s + 0] = fmaf(cc, lo, acc[s + 0]);                 \
                        acc[s + 1] = fmaf(cc, hi, acc[s + 1]);                 \
                    }
                    EDGEFMA(w0, c0)
                    EDGEFMA(w1, c1)
                    EDGEFMA(w2, c2)
                    EDGEFMA(w3, c3)
#undef EDGEFMA
                }
            }
        }

        ushort_t* grow = Gl + lnode * STRIDE;
        ushort_t* gp = grow + k * CIN + i0;
#pragma unroll
        for (int q = 0; q < NU4; ++q) {
            uint4 o;
            o.x = (unsigned int)f2bf(acc[q*8+0]) | ((unsigned int)f2bf(acc[q*8+1]) << 16);
            o.y = (unsigned int)f2bf(acc[q*8+2]) | ((unsigned int)f2bf(acc[q*8+3]) << 16);
            o.z = (unsigned int)f2bf(acc[q*8+4]) | ((unsigned int)f2bf(acc[q*8+5]) << 16);
            o.w = (unsigned int)f2bf(acc[q*8+6]) | ((unsigned int)f2bf(acc[q*8+7]) << 16);
            *(uint4*)(gp + q * 8) = o;
        }
        for (int i = lane; i < CIN; i += 64) {
            ushort_t v = Xb[(size_t)n * CIN + i];
            if (RELU && (v & 0x8000)) v = 0;
            grow[16 * CIN + i] = v;
        }
    }
    __syncthreads();

    const int ot = wv & 3;
    const int kh = wv >> 2;
    f32x4 cacc = {0.f, 0.f, 0.f, 0.f};
    const ushort_t* garow = Gl + (lane & 15) * STRIDE + ((lane >> 4) << 3);
    const ushort_t* wpp = Wp + ((size_t)(ot * 64 + lane) << 3);
    for (int ks = kh; ks < KSTEPS; ks += 2) {
        bf16x8 a = *(const bf16x8*)(garow + ks * 32);
        bf16x8 b = *(const bf16x8*)(wpp + (size_t)ks * 2048);
        cacc = __builtin_amdgcn_mfma_f32_16x16x32_bf16(a, b, cacc, 0, 0, 0);
    }
    if (kh == 1) {
        red[ot][lane][0] = cacc[0];
        red[ot][lane][1] = cacc[1];
        red[ot][lane][2] = cacc[2];
        red[ot][lane][3] = cacc[3];
    }
    __syncthreads();
    if (kh == 0) {
        int o = ot * 16 + (lane & 15);
        float bo = bias[o];
#pragma unroll
        for (int r = 0; r < 4; ++r) {
            int node = nb + ((lane >> 4) << 2) + r;
            if (node < NF) {
                float s = cacc[r] + red[ot][lane][r] + bo;
                if (RESID) s += bf2f(XresB[(size_t)node * 64 + o]);
                if (FINAL) {
                    ((float*)OUT)[(size_t)node * 64 + o] = s * (1.0f / 128.0f);
                } else {
                    ((ushort_t*)OUT)[(size_t)node * 64 + o] = f2bf(s);
                }
            }
        }
    }
}

extern "C" void kernel_launch(void* const* d_in, const int* in_sizes, int n_in,
                              void* d_out, int out_size, void* d_ws, size_t ws_size,
                              hipStream_t stream) {
    const float* fluidPos      = (const float*)d_in[0];
    const float* boundaryPos   = (const float*)d_in[1];
    const float* fluidFeats    = (const float*)d_in[2];
    const float* boundaryFeats = (const float*)d_in[3];
    const int* fe_i = (const int*)d_in[4];
    const int* fe_j = (const int*)d_in[5];
    const int* be_f = (const int*)d_in[6];
    const int* be_b = (const int*)d_in[7];
    const float* W[8];
    const float* bb[8];
    for (int c = 0; c < 8; ++c) {
        W[c]  = (const float*)d_in[8 + 2 * c];
        bb[c] = (const float*)d_in[9 + 2 * c];
    }
    const float* fcW0 = (const float*)d_in[24];
    const float* fcb0 = (const float*)d_in[25];
    const float* fcW1 = (const float*)d_in[26];
    const float* fcb1 = (const float*)d_in[27];
    const float* fcW2 = (const float*)d_in[28];
    const float* fcb2 = (const float*)d_in[29];

    int NF = in_sizes[0] / 2;
    int EF = in_sizes[4];
    int EB = in_sizes[6];

    // ---- workspace layout (f32 units) ----
    float* ws = (float*)d_ws;
    size_t p = 0;
    float* f_coeff = ws + p;  p += (size_t)EF * 16;
    float* b_coeff = ws + p;  p += (size_t)EB * 16;
    ushort_t* A1b  = (ushort_t*)(ws + p);  p += (size_t)NF * 48;   // NF*96 bf16
    ushort_t* ans2b= (ushort_t*)(ws + p);  p += (size_t)NF * 32;   // NF*64 bf16
    int*   f_off   = (int*)(ws + p);  p += (size_t)((NF + 4) & ~3);
    int*   b_off   = (int*)(ws + p);  p += (size_t)((NF + 4) & ~3);
    ushort_t* Wp2  = (ushort_t*)(ws + p);  p += 1632 * 32;   // 1632*64 bf16
    float* bias2   = ws + p;  p += 64;
    ushort_t* Wp3  = (ushort_t*)(ws + p);  p += 1088 * 32;
    float* bias3   = ws + p;  p += 64;

    int totalPro = EF + EB + 2 * (NF + 1) + 64 + 51 * 2048 + 64 + 34 * 2048;
    prologue_kernel<<<(totalPro + 255) / 256, 256, 0, stream>>>(
        (const float2*)fluidPos, (const float2*)boundaryPos,
        fe_i, fe_j, be_f, be_b,
        W[4], W[5], fcW1, bb[4], bb[5], fcb1,
        W[6], W[7], fcW2, bb[6], bb[7], fcb2,
        f_coeff, b_coeff, f_off, b_off,
        Wp2, bias2, Wp3, bias3, EF, EB, NF);

    layer1_kernel<<<NF, 128, 0, stream>>>(fluidFeats, boundaryFeats, fcW0, fcb0,
                                          W[0], bb[0], W[1], bb[1], W[2], bb[2], W[3], bb[3],
                                          f_off, fe_j, f_coeff, b_off, be_b, b_coeff, A1b);

    int nblk = (NF + 15) / 16;
    conv_mfma_kernel<96, false, false, false><<<nblk, 512, 0, stream>>>(
        A1b, f_off, fe_j, f_coeff, Wp2, bias2, nullptr, ans2b, NF);
    conv_mfma_kernel<64, true, true, true><<<nblk, 512, 0, stream>>>(
        ans2b, f_off, fe_j, f_coeff, Wp3, bias3, ans2b, d_out, NF);
}